// Round 2
// baseline (5291.599 us; speedup 1.0000x reference)
//
#include <hip/hip_runtime.h>
#include <math.h>

// ---------------------------------------------------------------------------
// SO2 equivariant graph attention. N=10000, E=100000, L2=16, C=64, H=32, R=64.
// Slot order s=0..13 (wigner row IDX[s], equals vals row order):
//   M0={0,2,6,12}, M1P={3,7,13}(y1r), M1N={1,5,11}(y1i), M2P={8,14}(y2r), M2N={4,10}(y2i)
// Pipeline: init | gate | k_gemm(rotate+SO2 GEMM+gate+logits -> vals,logits)
//           | segmax | segden | k_scatter(attn+invrot+atomic agg) | k_out
// ---------------------------------------------------------------------------

__constant__ int c_ROWS14[14] = {0,2,6,12, 3,7,13, 1,5,11, 8,14, 4,10};

__device__ __forceinline__ unsigned enc_f(float f){
  unsigned u = __float_as_uint(f);
  return (u & 0x80000000u) ? ~u : (u | 0x80000000u);
}
__device__ __forceinline__ float dec_f(unsigned u){
  return (u & 0x80000000u) ? __uint_as_float(u & 0x7fffffffu)
                           : __uint_as_float(~u);
}

// ------------------------------ init ---------------------------------------
__global__ void k_init(float* __restrict__ agg, unsigned* __restrict__ mxe,
                       float* __restrict__ den, int N){
  const int idx = blockIdx.x*256 + threadIdx.x;
  if(idx < N*512) agg[idx] = 0.f;
  if(idx < N*8){ mxe[idx] = 0u; den[idx] = 0.f; }
}

// ------------------------------ gate ---------------------------------------
__global__ __launch_bounds__(256)
void k_gate(const float* __restrict__ rbf, const float* __restrict__ Wr1,
            const float* __restrict__ Wr2, float* __restrict__ gate){
  __shared__ float s_r[4][64];
  __shared__ float s_t[4][64];
  const int le = threadIdx.x >> 6, ln = threadIdx.x & 63;
  const int e = blockIdx.x*4 + le;
  s_r[le][ln] = rbf[(size_t)e*64 + ln];
  __syncthreads();
  float acc = 0.f;
  #pragma unroll 8
  for(int k=0;k<64;k++) acc = fmaf(s_r[le][k], Wr1[k*64+ln], acc);
  const float sg = 1.f/(1.f + __expf(-acc));
  s_t[le][ln] = acc*sg;                      // silu
  __syncthreads();
  if(ln < 32){
    float a2 = 0.f;
    #pragma unroll 8
    for(int k=0;k<64;k++) a2 = fmaf(s_t[le][k], Wr2[k*32+ln], a2);
    gate[(size_t)e*32 + ln] = 1.f/(1.f + __expf(-a2));
  }
}

// ------------------------------ k_gemm -------------------------------------
// 16 edges/block, 128 threads.  LDS: sA[384][16] (k x edge, b128 broadcast
// reads), sWigG[16][NR*16+1].  B read straight from L1/L2 in the k-loop.
// Per-thread tile: 8 edges x Ot outs.  Writes gated vals [E][448] + logits.
template<int G>
__device__ __forceinline__ void group_pass(
    float* __restrict__ sA, float* __restrict__ sWigG,
    const float* __restrict__ x, const float* __restrict__ wig,
    const float* __restrict__ W0, const float* __restrict__ W1r,
    const float* __restrict__ W1i, const float* __restrict__ W2r,
    const float* __restrict__ W2i, const float* __restrict__ gate,
    const float* __restrict__ alpha, const int* __restrict__ src,
    const int* __restrict__ dst, float* __restrict__ vals,
    float* __restrict__ logits, int e0)
{
  constexpr int NR  = (G==1)?6:4;                 // rows in this group
  constexpr int NRA = (G==0)?4:((G==1)?3:2);      // rows in "real" phase
  constexpr int Ot  = (G==1)?3:2;                 // outs per thread
  constexpr int LD  = (G==0)?128:((G==1)?96:64);  // W leading dim
  constexpr int VB  = (G==0)?0:((G==1)?128:320);  // vals col base
  constexpr int SB  = (G==0)?0:((G==1)?4:10);     // slot base
  constexpr int NRp = NR*16+1;
  const int t = threadIdx.x;

  __syncthreads();                                // prev group fully done
  // ---- stage wigner rows for this group: 16 edges x NR x 16 ----
  for(int tau=t; tau<16*NR*16; tau+=128){
    const int el = tau/(NR*16), q = tau%(NR*16);
    sWigG[el*NRp + q] =
        wig[(size_t)(e0+el)*256 + c_ROWS14[SB+(q>>4)]*16 + (q&15)];
  }
  __syncthreads();

  const int eg = t>>6, tid_o = t&63;
  const int o0 = tid_o*Ot;
  float accP[8][Ot], accN[8][Ot];
  #pragma unroll
  for(int i=0;i<8;i++)
    #pragma unroll
    for(int j=0;j<Ot;j++){ accP[i][j]=0.f; accN[i][j]=0.f; }

  // per-thread B base pointers (column o0 of the sign-assembled block matrix)
  const float* pA; const float* pB = nullptr;
  if(G==0){ pA = W0 + o0; }
  else if(G==1){
    pA = (o0<96)? (W1r+o0) : (W1i+(o0-96));
    pB = (o0<96)? (W1i+o0) : (W1r+(o0-96));
  } else {
    pA = (o0<64)? (W2r+o0) : (W2i+(o0-64));
    pB = (o0<64)? (W2i+o0) : (W2r+(o0-64));
  }

  for(int half=0; half<2; half++){
    // ---- build rotated A (all NR rows), x row read once per (edge,half) ----
    #pragma unroll
    for(int p2=0;p2<2;p2++){
      const int tau = p2*128 + t;
      const int bel = tau&15, bc4 = tau>>4;
      const int node = (half ? dst : src)[e0+bel];
      const float* xp = x + (size_t)node*1024 + bc4*4;
      const float* wr = &sWigG[bel*NRp];
      float4 a[NR];
      #pragma unroll
      for(int r=0;r<NR;r++){ a[r].x=0.f; a[r].y=0.f; a[r].z=0.f; a[r].w=0.f; }
      #pragma unroll
      for(int j=0;j<16;j++){
        const float4 xv = *(const float4*)(xp + j*64);
        #pragma unroll
        for(int r=0;r<NR;r++){
          const float w = wr[r*16+j];
          a[r].x = fmaf(w, xv.x, a[r].x); a[r].y = fmaf(w, xv.y, a[r].y);
          a[r].z = fmaf(w, xv.z, a[r].z); a[r].w = fmaf(w, xv.w, a[r].w);
        }
      }
      #pragma unroll
      for(int r=0;r<NR;r++){
        const int kb = (r*64 + bc4*4)*16 + bel;
        sA[kb] = a[r].x; sA[kb+16] = a[r].y; sA[kb+32] = a[r].z; sA[kb+48] = a[r].w;
      }
    }
    __syncthreads();

    // ---- GEMM: Et=8 edges (one wave per edge-octet -> broadcast A reads) ----
    auto gemm_rows = [&](int rbeg, int rend, const float* pbase,
                         float (*acc)[Ot]){
      for(int r=rbeg; r<rend; r++){
        const float* p = pbase + (size_t)((r-rbeg)*128 + half*64)*LD;
        #pragma unroll 4
        for(int cc=0; cc<64; cc++){
          const int kk = (r*64+cc)*16 + eg*8;
          const float4 a0 = *(const float4*)&sA[kk];
          const float4 a1 = *(const float4*)&sA[kk+4];
          const float* pk = p + cc*LD;
          #pragma unroll
          for(int j=0;j<Ot;j++){
            const float b = pk[j];
            acc[0][j] = fmaf(a0.x,b,acc[0][j]);
            acc[1][j] = fmaf(a0.y,b,acc[1][j]);
            acc[2][j] = fmaf(a0.z,b,acc[2][j]);
            acc[3][j] = fmaf(a0.w,b,acc[3][j]);
            acc[4][j] = fmaf(a1.x,b,acc[4][j]);
            acc[5][j] = fmaf(a1.y,b,acc[5][j]);
            acc[6][j] = fmaf(a1.z,b,acc[6][j]);
            acc[7][j] = fmaf(a1.w,b,acc[7][j]);
          }
        }
      }
    };
    gemm_rows(0, NRA, pA, accP);
    if(NRA < NR) gemm_rows(NRA, NR, pB, accN);
    if(half==0) __syncthreads();      // sA rebuilt next half
  }

  // ---- epilogue: combine phases, apply gate, store vals (+ logits for G0) ----
  const float sg = (G==1) ? ((o0<96)?-1.f:1.f)
                 : (G==2) ? ((o0<64)?-1.f:1.f) : 0.f;
  #pragma unroll
  for(int i=0;i<8;i++){
    const int e = e0 + eg*8 + i;
    float y[Ot];
    #pragma unroll
    for(int j=0;j<Ot;j++){
      const float g = gate[(size_t)e*32 + ((o0+j)&31)];
      float v = accP[i][j];
      if(NRA < NR) v = fmaf(sg, accN[i][j], v);
      y[j] = v*g;
      vals[(size_t)e*448 + VB + o0 + j] = y[j];
    }
    if(G==0 && tid_o<16){
      const float z0 = (y[0]>0.f)? y[0] : 0.2f*y[0];
      const float z1 = (y[1]>0.f)? y[1] : 0.2f*y[1];
      float ct = z0*alpha[o0] + z1*alpha[o0+1];
      ct += __shfl_xor(ct, 1);
      if(!(tid_o&1)) logits[(size_t)e*8 + (tid_o>>1)] = ct;
    }
  }
}

__global__ __launch_bounds__(128)
void k_gemm(const float* __restrict__ x, const float* __restrict__ wig,
            const float* __restrict__ W0, const float* __restrict__ W1r,
            const float* __restrict__ W1i, const float* __restrict__ W2r,
            const float* __restrict__ W2i, const float* __restrict__ gate,
            const float* __restrict__ alpha, const int* __restrict__ src,
            const int* __restrict__ dst, float* __restrict__ vals,
            float* __restrict__ logits)
{
  __shared__ float sA[384*16];
  __shared__ float sWigG[16*97];
  const int e0 = blockIdx.x*16;
  group_pass<0>(sA,sWigG,x,wig,W0,W1r,W1i,W2r,W2i,gate,alpha,src,dst,vals,logits,e0);
  group_pass<1>(sA,sWigG,x,wig,W0,W1r,W1i,W2r,W2i,gate,alpha,src,dst,vals,logits,e0);
  group_pass<2>(sA,sWigG,x,wig,W0,W1r,W1i,W2r,W2i,gate,alpha,src,dst,vals,logits,e0);
}

// --------------------------- segment softmax -------------------------------
__global__ void k_max(const float* __restrict__ logits, const int* __restrict__ dst,
                      unsigned* __restrict__ mxe, int E8){
  const int idx = blockIdx.x*256 + threadIdx.x;
  if(idx >= E8) return;
  const int e = idx>>3, hd = idx&7;
  atomicMax(&mxe[(size_t)dst[e]*8 + hd], enc_f(logits[idx]));
}
__global__ void k_den(const float* __restrict__ logits, const int* __restrict__ dst,
                      const unsigned* __restrict__ mxe, float* __restrict__ den, int E8){
  const int idx = blockIdx.x*256 + threadIdx.x;
  if(idx >= E8) return;
  const int e = idx>>3, hd = idx&7;
  const float m = dec_f(mxe[(size_t)dst[e]*8 + hd]);
  atomicAdd(&den[(size_t)dst[e]*8 + hd], __expf(logits[idx] - m));
}

// ------------------------------ k_scatter ----------------------------------
// 16 edges/block, 256 threads: attn weight + inverse rotation + atomic agg.
__global__ __launch_bounds__(256)
void k_scatter(const float* __restrict__ vals, const float* __restrict__ wig,
               const float* __restrict__ logits, const unsigned* __restrict__ mxe,
               const float* __restrict__ den, const int* __restrict__ dst,
               float* __restrict__ agg)
{
  __shared__ float sV[16*452];
  __shared__ float sWg[16*225];
  const int t = threadIdx.x;
  const int e0 = blockIdx.x*16;
  #pragma unroll
  for(int p=0;p<7;p++){
    const int tau = p*256 + t;
    const int el = tau/112, q4 = tau%112;
    *(float4*)&sV[el*452 + q4*4] =
        *(const float4*)&vals[(size_t)(e0+el)*448 + q4*4];
  }
  #pragma unroll
  for(int p=0;p<14;p++){
    const int tau = p*256 + t;
    const int el = tau/224, q = tau%224;
    sWg[el*225 + q] =
        wig[(size_t)(e0+el)*256 + c_ROWS14[q>>4]*16 + (q&15)];
  }
  __syncthreads();

  const int el = t>>4, i = t&15;
  const int e = e0 + el;
  const int dn = dst[e];
  float at[8];
  #pragma unroll
  for(int hd=0;hd<8;hd++){
    const float m = dec_f(mxe[(size_t)dn*8 + hd]);
    at[hd] = __expf(logits[(size_t)e*8 + hd] - m) / den[(size_t)dn*8 + hd];
  }
  float4 msg[8];
  #pragma unroll
  for(int h4=0;h4<8;h4++){ msg[h4].x=0.f; msg[h4].y=0.f; msg[h4].z=0.f; msg[h4].w=0.f; }
  #pragma unroll
  for(int s=0;s<14;s++){
    const float w = sWg[el*225 + s*16 + i];
    #pragma unroll
    for(int h4=0;h4<8;h4++){
      const float4 v = *(const float4*)&sV[el*452 + s*32 + h4*4];
      msg[h4].x = fmaf(w, v.x, msg[h4].x);
      msg[h4].y = fmaf(w, v.y, msg[h4].y);
      msg[h4].z = fmaf(w, v.z, msg[h4].z);
      msg[h4].w = fmaf(w, v.w, msg[h4].w);
    }
  }
  float* ag = agg + (size_t)dn*512 + i*32;
  #pragma unroll
  for(int h4=0;h4<8;h4++){
    const float a = at[h4];
    atomicAdd(&ag[h4*4+0], msg[h4].x*a);
    atomicAdd(&ag[h4*4+1], msg[h4].y*a);
    atomicAdd(&ag[h4*4+2], msg[h4].z*a);
    atomicAdd(&ag[h4*4+3], msg[h4].w*a);
  }
}

// ------------------------------ output -------------------------------------
__global__ __launch_bounds__(256)
void k_out(const float* __restrict__ agg, const float* __restrict__ Wout,
           float* __restrict__ out, int total4){
  const int idx = blockIdx.x*256 + threadIdx.x;
  if(idx >= total4) return;
  const int c4 = idx & 15, row = idx >> 4;      // row = n*16+i
  const float* ap = agg + (size_t)row*32;
  float4 acc; acc.x=0.f; acc.y=0.f; acc.z=0.f; acc.w=0.f;
  #pragma unroll
  for(int h=0;h<32;h++){
    const float a = ap[h];
    const float4 w = *(const float4*)&Wout[h*64 + c4*4];
    acc.x = fmaf(a, w.x, acc.x); acc.y = fmaf(a, w.y, acc.y);
    acc.z = fmaf(a, w.z, acc.z); acc.w = fmaf(a, w.w, acc.w);
  }
  *(float4*)&out[(size_t)row*64 + c4*4] = acc;
}

// ---------------------------------------------------------------------------
extern "C" void kernel_launch(void* const* d_in, const int* in_sizes, int n_in,
                              void* d_out, int out_size, void* d_ws, size_t ws_size,
                              hipStream_t stream){
  const float* x     = (const float*)d_in[0];
  const float* wig   = (const float*)d_in[1];
  const float* rbf   = (const float*)d_in[2];
  const float* W0    = (const float*)d_in[3];
  const float* W1r   = (const float*)d_in[4];
  const float* W1i   = (const float*)d_in[5];
  const float* W2r   = (const float*)d_in[6];
  const float* W2i   = (const float*)d_in[7];
  const float* Wr1   = (const float*)d_in[8];
  const float* Wr2   = (const float*)d_in[9];
  const float* alpha = (const float*)d_in[10];
  const float* Wout  = (const float*)d_in[11];
  const int*   src   = (const int*)d_in[12];
  const int*   dst   = (const int*)d_in[13];
  float* out = (float*)d_out;

  const int E = in_sizes[12];
  const int N = in_sizes[0] / 1024;       // x is [N,16,64]

  // ws (floats): gate E*32 | logits E*8 | mxe N*8 | den N*8 | agg N*512 | vals E*448
  float*    ws     = (float*)d_ws;
  float*    gate   = ws;
  float*    logits = ws + (size_t)E*32;
  unsigned* mxe    = (unsigned*)(ws + (size_t)E*40);
  float*    den    = ws + (size_t)E*40 + (size_t)N*8;
  float*    agg    = ws + (size_t)E*40 + (size_t)N*16;
  float*    vals   = ws + (size_t)E*40 + (size_t)N*16 + (size_t)N*512;

  k_init   <<<(N*512 + 255)/256, 256, 0, stream>>>(agg, mxe, den, N);
  k_gate   <<<E/4, 256, 0, stream>>>(rbf, Wr1, Wr2, gate);
  k_gemm   <<<E/16, 128, 0, stream>>>(x, wig, W0, W1r, W1i, W2r, W2i,
                                      gate, alpha, src, dst, vals, logits);
  k_max    <<<(E*8 + 255)/256, 256, 0, stream>>>(logits, dst, mxe, E*8);
  k_den    <<<(E*8 + 255)/256, 256, 0, stream>>>(logits, dst, mxe, den, E*8);
  k_scatter<<<E/16, 256, 0, stream>>>(vals, wig, logits, mxe, den, dst, agg);
  k_out    <<<(N*16*16 + 255)/256, 256, 0, stream>>>(agg, Wout, out, N*16*16);
}

// Round 4
// 2264.882 us; speedup vs baseline: 2.3364x; 2.3364x over previous
//
#include <hip/hip_runtime.h>
#include <math.h>

// ---------------------------------------------------------------------------
// SO2 equivariant graph attention. N=10000, E=100000, L2=16, C=64, H=32, R=64.
// Slot order s=0..13 (wigner row IDX[s], equals vals row order):
//   M0={0,2,6,12}, M1P={3,7,13}(y1r), M1N={1,5,11}(y1i), M2P={8,14}(y2r), M2N={4,10}(y2i)
// Pipeline: init | CSR(count,scan,fill) | gate | k_so2<0,1,2> (rotate+GEMM+
//   gate+logits -> vals,logits) | segmax | segden | k_agg (attn+invrot+Wout -> out)
// ---------------------------------------------------------------------------

__constant__ int c_ROWS14[14] = {0,2,6,12, 3,7,13, 1,5,11, 8,14, 4,10};

__device__ __forceinline__ unsigned enc_f(float f){
  unsigned u = __float_as_uint(f);
  return (u & 0x80000000u) ? ~u : (u | 0x80000000u);
}
__device__ __forceinline__ float dec_f(unsigned u){
  return (u & 0x80000000u) ? __uint_as_float(u & 0x7fffffffu)
                           : __uint_as_float(~u);
}

// ------------------------------ init / CSR ---------------------------------
__global__ void k_init(unsigned* __restrict__ mxe, float* __restrict__ den, int N8){
  const int idx = blockIdx.x*256 + threadIdx.x;
  if(idx < N8){ mxe[idx] = 0u; den[idx] = 0.f; }
}
__global__ void k_zero(int* __restrict__ deg, int N){
  const int idx = blockIdx.x*256 + threadIdx.x;
  if(idx < N) deg[idx] = 0;
}
__global__ void k_count(const int* __restrict__ dst, int* __restrict__ deg, int E){
  const int e = blockIdx.x*256 + threadIdx.x;
  if(e < E) atomicAdd(&deg[dst[e]], 1);
}
__global__ __launch_bounds__(1024)
void k_scan(const int* __restrict__ deg, int* __restrict__ ptr,
            int* __restrict__ cursor, int N){
  __shared__ int sPart[1024];
  const int t = threadIdx.x;
  const int per = (N + 1023) >> 10;
  const int base = t*per;
  int s = 0;
  for(int k=0;k<per;k++){ const int idx=base+k; s += (idx<N)? deg[idx] : 0; }
  sPart[t] = s;
  __syncthreads();
  for(int off=1; off<1024; off<<=1){
    const int v = (t>=off)? sPart[t-off] : 0;
    __syncthreads();
    sPart[t] += v;
    __syncthreads();
  }
  int run = (t==0)? 0 : sPart[t-1];
  for(int k=0;k<per;k++){
    const int idx=base+k;
    if(idx<N){ ptr[idx]=run; cursor[idx]=run; run += deg[idx]; }
  }
  if(t==1023) ptr[N] = sPart[1023];
}
__global__ void k_fill(const int* __restrict__ dst, int* __restrict__ cursor,
                       int* __restrict__ eidx, int E){
  const int e = blockIdx.x*256 + threadIdx.x;
  if(e >= E) return;
  const int pos = atomicAdd(&cursor[dst[e]], 1);
  eidx[pos] = e;
}

// ------------------------------ gate ---------------------------------------
__global__ __launch_bounds__(256)
void k_gate(const float* __restrict__ rbf, const float* __restrict__ Wr1,
            const float* __restrict__ Wr2, float* __restrict__ gate){
  __shared__ float s_r[4][64];
  __shared__ float s_t[4][64];
  const int le = threadIdx.x >> 6, ln = threadIdx.x & 63;
  const int e = blockIdx.x*4 + le;
  s_r[le][ln] = rbf[(size_t)e*64 + ln];
  __syncthreads();
  float acc = 0.f;
  #pragma unroll 8
  for(int k=0;k<64;k++) acc = fmaf(s_r[le][k], Wr1[k*64+ln], acc);
  const float sg = 1.f/(1.f + __expf(-acc));
  s_t[le][ln] = acc*sg;                      // silu
  __syncthreads();
  if(ln < 32){
    float a2 = 0.f;
    #pragma unroll 8
    for(int k=0;k<64;k++) a2 = fmaf(s_t[le][k], Wr2[k*32+ln], a2);
    gate[(size_t)e*32 + ln] = 1.f/(1.f + __expf(-a2));
  }
}

// ------------------------------ k_so2<G> -----------------------------------
// 16 edges/block, 128 threads.  LDS: sA[NR*64][16] (k x edge; GEMM reads are
// wave-broadcast), sWigG.  B from L1/L2, vectorized + 4-row prefetch.
template<int Ot>
__device__ __forceinline__ void ldB(const float* __restrict__ p, float* __restrict__ r){
  if constexpr(Ot==2){ const float2 u = *(const float2*)p; r[0]=u.x; r[1]=u.y; }
  else { r[0]=p[0]; r[1]=p[1]; r[2]=p[2]; }
}

template<int G>
__global__ __launch_bounds__(128, 4)
void k_so2(const float* __restrict__ x, const float* __restrict__ wig,
           const float* __restrict__ W0, const float* __restrict__ W1r,
           const float* __restrict__ W1i, const float* __restrict__ W2r,
           const float* __restrict__ W2i, const float* __restrict__ gate,
           const float* __restrict__ alpha, const int* __restrict__ src,
           const int* __restrict__ dst, float* __restrict__ vals,
           float* __restrict__ logits)
{
  constexpr int NR  = (G==1)?6:4;                 // rows in this group
  constexpr int NRA = (G==0)?4:((G==1)?3:2);      // rows in "real" phase
  constexpr int Ot  = (G==1)?3:2;                 // outs per thread
  constexpr int LD  = (G==0)?128:((G==1)?96:64);  // W leading dim
  constexpr int VB  = (G==0)?0:((G==1)?128:320);  // vals col base
  constexpr int SB  = (G==0)?0:((G==1)?4:10);     // slot base
  constexpr int NRp = NR*16+1;
  __shared__ float sA[NR*64*16];
  __shared__ float sWigG[16*NRp];
  const int t  = threadIdx.x;
  const int e0 = blockIdx.x*16;

  for(int tau=t; tau<16*NR*16; tau+=128){
    const int el = tau/(NR*16), q = tau%(NR*16);
    sWigG[el*NRp + q] =
        wig[(size_t)(e0+el)*256 + c_ROWS14[SB+(q>>4)]*16 + (q&15)];
  }
  __syncthreads();

  const int eg = t>>6, tid_o = t&63;
  const int o0 = tid_o*Ot;
  float accP[8][Ot], accN[8][Ot];
  #pragma unroll
  for(int i=0;i<8;i++)
    #pragma unroll
    for(int j=0;j<Ot;j++){ accP[i][j]=0.f; accN[i][j]=0.f; }

  const float* pA; const float* pB = nullptr;
  if(G==0){ pA = W0 + o0; }
  else if(G==1){
    pA = (o0<96)? (W1r+o0) : (W1i+(o0-96));
    pB = (o0<96)? (W1i+o0) : (W1r+(o0-96));
  } else {
    pA = (o0<64)? (W2r+o0) : (W2i+(o0-64));
    pB = (o0<64)? (W2i+o0) : (W2r+(o0-64));
  }

  for(int half=0; half<2; half++){
    // ---- build rotated A; x row read once per (edge,half) ----
    #pragma unroll
    for(int p2=0;p2<2;p2++){
      const int tau = p2*128 + t;
      const int bel = tau&15, bc4 = tau>>4;
      const int node = (half ? dst : src)[e0+bel];
      const float* xp = x + (size_t)node*1024 + bc4*4;
      const float* wr = &sWigG[bel*NRp];
      float4 a[NR];
      #pragma unroll
      for(int r=0;r<NR;r++){ a[r].x=0.f; a[r].y=0.f; a[r].z=0.f; a[r].w=0.f; }
      #pragma unroll
      for(int j=0;j<16;j++){
        const float4 xv = *(const float4*)(xp + j*64);
        #pragma unroll
        for(int r=0;r<NR;r++){
          const float w = wr[r*16+j];
          a[r].x = fmaf(w, xv.x, a[r].x); a[r].y = fmaf(w, xv.y, a[r].y);
          a[r].z = fmaf(w, xv.z, a[r].z); a[r].w = fmaf(w, xv.w, a[r].w);
        }
      }
      #pragma unroll
      for(int r=0;r<NR;r++){
        const int kb = (r*64 + bc4*4)*16 + bel;
        sA[kb] = a[r].x; sA[kb+16] = a[r].y; sA[kb+32] = a[r].z; sA[kb+48] = a[r].w;
      }
    }
    __syncthreads();

    // ---- GEMM: per wave one edge-octet (broadcast sA reads), prefetched B ----
    auto gemm_rows = [&](int rbeg, int rend, const float* pbase, float (*acc)[Ot]){
      for(int r=rbeg; r<rend; r++){
        const float* p = pbase + (size_t)((r-rbeg)*128 + half*64)*LD;
        float b[4][Ot], nb[4][Ot];
        #pragma unroll
        for(int q=0;q<4;q++) ldB<Ot>(p + q*LD, b[q]);
        for(int cc4=0; cc4<16; cc4++){
          const bool more = (cc4 < 15);
          if(more){
            #pragma unroll
            for(int q=0;q<4;q++) ldB<Ot>(p + (cc4*4+4+q)*LD, nb[q]);
          }
          #pragma unroll
          for(int q=0;q<4;q++){
            const int cc = cc4*4+q;
            const float* ap = &sA[(r*64+cc)*16 + eg*8];
            const float4 a0 = *(const float4*)ap;
            const float4 a1 = *(const float4*)(ap+4);
            #pragma unroll
            for(int j=0;j<Ot;j++){
              const float bb = b[q][j];
              acc[0][j] = fmaf(a0.x,bb,acc[0][j]);
              acc[1][j] = fmaf(a0.y,bb,acc[1][j]);
              acc[2][j] = fmaf(a0.z,bb,acc[2][j]);
              acc[3][j] = fmaf(a0.w,bb,acc[3][j]);
              acc[4][j] = fmaf(a1.x,bb,acc[4][j]);
              acc[5][j] = fmaf(a1.y,bb,acc[5][j]);
              acc[6][j] = fmaf(a1.z,bb,acc[6][j]);
              acc[7][j] = fmaf(a1.w,bb,acc[7][j]);
            }
          }
          if(more){
            #pragma unroll
            for(int q=0;q<4;q++)
              #pragma unroll
              for(int j=0;j<Ot;j++) b[q][j] = nb[q][j];
          }
        }
      }
    };
    gemm_rows(0, NRA, pA, accP);
    if(NRA < NR) gemm_rows(NRA, NR, pB, accN);
    if(half==0) __syncthreads();      // sA rebuilt next half
  }

  // ---- epilogue: combine, gate, store vals (+ logits for G0) ----
  const float sg = (G==1) ? ((o0<96)?-1.f:1.f)
                 : (G==2) ? ((o0<64)?-1.f:1.f) : 0.f;
  #pragma unroll
  for(int i=0;i<8;i++){
    const int e = e0 + eg*8 + i;
    float y[Ot];
    #pragma unroll
    for(int j=0;j<Ot;j++){
      const float g = gate[(size_t)e*32 + ((o0+j)&31)];
      float v = accP[i][j];
      if(NRA < NR) v = fmaf(sg, accN[i][j], v);
      y[j] = v*g;
      vals[(size_t)e*448 + VB + o0 + j] = y[j];
    }
    if(G==0 && tid_o<16){
      const float z0 = (y[0]>0.f)? y[0] : 0.2f*y[0];
      const float z1 = (y[1]>0.f)? y[1] : 0.2f*y[1];
      float ct = z0*alpha[o0] + z1*alpha[o0+1];
      ct += __shfl_xor(ct, 1);
      if(!(tid_o&1)) logits[(size_t)e*8 + (tid_o>>1)] = ct;
    }
  }
}

// --------------------------- segment softmax -------------------------------
__global__ void k_max(const float* __restrict__ logits, const int* __restrict__ dst,
                      unsigned* __restrict__ mxe, int E8){
  const int idx = blockIdx.x*256 + threadIdx.x;
  if(idx >= E8) return;
  const int e = idx>>3, hd = idx&7;
  atomicMax(&mxe[(size_t)dst[e]*8 + hd], enc_f(logits[idx]));
}
__global__ void k_den(const float* __restrict__ logits, const int* __restrict__ dst,
                      const unsigned* __restrict__ mxe, float* __restrict__ den, int E8){
  const int idx = blockIdx.x*256 + threadIdx.x;
  if(idx >= E8) return;
  const int e = idx>>3, hd = idx&7;
  const float m = dec_f(mxe[(size_t)dst[e]*8 + hd]);
  atomicAdd(&den[(size_t)dst[e]*8 + hd], __expf(logits[idx] - m));
}

// ------------------------------ k_agg --------------------------------------
// One block per destination node: gather CSR edges, attn-weight + inverse
// rotation accumulated in registers, then fused W_out projection -> out.
// No global atomics.
__global__ __launch_bounds__(256)
void k_agg(const float* __restrict__ vals, const float* __restrict__ wig,
           const float* __restrict__ logits, const unsigned* __restrict__ mxe,
           const float* __restrict__ den, const int* __restrict__ ptr,
           const int* __restrict__ eidx, const float* __restrict__ Wout,
           float* __restrict__ out)
{
  __shared__ float sV[2][448];
  __shared__ float sW[2][224];
  __shared__ float sAt[2][8];
  __shared__ float sWo[2048];
  __shared__ float sAgg[16*34];
  const int n = blockIdx.x;
  const int t = threadIdx.x;
  const int beg = ptr[n], deg = ptr[n+1]-beg;
  const int i = t>>4, hp = t&15;

  #pragma unroll
  for(int q=0;q<2;q++){
    const int idx = (q*256+t)*4;
    *(float4*)&sWo[idx] = *(const float4*)&Wout[idx];
  }

  auto stage = [&](int k, int buf){
    const int e = eidx[beg+k];
    if(t < 112){
      *(float4*)&sV[buf][t*4] = *(const float4*)&vals[(size_t)e*448 + t*4];
    } else if(t < 168){
      const int q4 = (t-112)*4;
      const int s = q4>>4, off = q4&15;
      *(float4*)&sW[buf][q4] =
          *(const float4*)&wig[(size_t)e*256 + c_ROWS14[s]*16 + off];
    } else if(t < 176){
      const int hd = t-168;
      const float m = dec_f(mxe[(size_t)n*8 + hd]);
      sAt[buf][hd] = __expf(logits[(size_t)e*8 + hd] - m) / den[(size_t)n*8 + hd];
    }
  };

  float acc0 = 0.f, acc1 = 0.f;
  if(deg > 0){
    stage(0, 0);
    __syncthreads();
    for(int k=0;k<deg;k++){
      const int buf = k&1;
      if(k+1 < deg) stage(k+1, buf^1);   // overlap next stage with compute
      const float at = sAt[buf][hp>>1];
      float m0 = 0.f, m1 = 0.f;
      #pragma unroll
      for(int s=0;s<14;s++){
        const float w = sW[buf][s*16 + i];
        const float2 v = *(const float2*)&sV[buf][s*32 + hp*2];
        m0 = fmaf(w, v.x, m0); m1 = fmaf(w, v.y, m1);
      }
      acc0 = fmaf(m0, at, acc0);
      acc1 = fmaf(m1, at, acc1);
      __syncthreads();
    }
  } else {
    __syncthreads();
  }

  // ---- fused output projection: out[n,i,:] = agg[i,:] @ Wout ----
  sAgg[i*34 + hp*2]   = acc0;
  sAgg[i*34 + hp*2+1] = acc1;
  __syncthreads();
  float4 o; o.x=0.f; o.y=0.f; o.z=0.f; o.w=0.f;
  const float* wo = &sWo[hp*4];
  #pragma unroll
  for(int h=0;h<32;h++){
    const float a = sAgg[i*34 + h];
    const float4 w = *(const float4*)&wo[h*64];
    o.x = fmaf(a, w.x, o.x); o.y = fmaf(a, w.y, o.y);
    o.z = fmaf(a, w.z, o.z); o.w = fmaf(a, w.w, o.w);
  }
  *(float4*)&out[((size_t)n*16 + i)*64 + hp*4] = o;
}

// ---------------------------------------------------------------------------
extern "C" void kernel_launch(void* const* d_in, const int* in_sizes, int n_in,
                              void* d_out, int out_size, void* d_ws, size_t ws_size,
                              hipStream_t stream){
  const float* x     = (const float*)d_in[0];
  const float* wig   = (const float*)d_in[1];
  const float* rbf   = (const float*)d_in[2];
  const float* W0    = (const float*)d_in[3];
  const float* W1r   = (const float*)d_in[4];
  const float* W1i   = (const float*)d_in[5];
  const float* W2r   = (const float*)d_in[6];
  const float* W2i   = (const float*)d_in[7];
  const float* Wr1   = (const float*)d_in[8];
  const float* Wr2   = (const float*)d_in[9];
  const float* alpha = (const float*)d_in[10];
  const float* Wout  = (const float*)d_in[11];
  const int*   src   = (const int*)d_in[12];
  const int*   dst   = (const int*)d_in[13];
  float* out = (float*)d_out;

  const int E = in_sizes[12];
  const int N = in_sizes[0] / 1024;       // x is [N,16,64]

  // ws (floats): gate E*32 | logits E*8 | mxe N*8 | den N*8 | vals E*448
  //              | deg N | ptr N+1 | cursor N | eidx E   (ints)
  float*    ws     = (float*)d_ws;
  float*    gate   = ws;
  float*    logits = ws + (size_t)E*32;
  unsigned* mxe    = (unsigned*)(ws + (size_t)E*40);
  float*    den    = ws + (size_t)E*40 + (size_t)N*8;
  float*    vals   = ws + (size_t)E*40 + (size_t)N*16;
  int*      deg    = (int*)(vals + (size_t)E*448);
  int*      ptr    = deg + N;
  int*      cursor = ptr + N + 1;
  int*      eidx   = cursor + N;

  k_init <<<(N*8 + 255)/256, 256, 0, stream>>>(mxe, den, N*8);
  k_zero <<<(N + 255)/256, 256, 0, stream>>>(deg, N);
  k_count<<<(E + 255)/256, 256, 0, stream>>>(dst, deg, E);
  k_scan <<<1, 1024, 0, stream>>>(deg, ptr, cursor, N);
  k_fill <<<(E + 255)/256, 256, 0, stream>>>(dst, cursor, eidx, E);
  k_gate <<<E/4, 256, 0, stream>>>(rbf, Wr1, Wr2, gate);
  k_so2<0><<<E/16, 128, 0, stream>>>(x, wig, W0, W1r, W1i, W2r, W2i,
                                     gate, alpha, src, dst, vals, logits);
  k_so2<1><<<E/16, 128, 0, stream>>>(x, wig, W0, W1r, W1i, W2r, W2i,
                                     gate, alpha, src, dst, vals, logits);
  k_so2<2><<<E/16, 128, 0, stream>>>(x, wig, W0, W1r, W1i, W2r, W2i,
                                     gate, alpha, src, dst, vals, logits);
  k_max  <<<(E*8 + 255)/256, 256, 0, stream>>>(logits, dst, mxe, E*8);
  k_den  <<<(E*8 + 255)/256, 256, 0, stream>>>(logits, dst, mxe, den, E*8);
  k_agg  <<<N, 256, 0, stream>>>(vals, wig, logits, mxe, den, ptr, eidx, Wout, out);
}